// Round 1
// baseline (4818.604 us; speedup 1.0000x reference)
//
#include <hip/hip_runtime.h>

#define H 128
#define NEG 0.2f
#define EPSBN 1e-5f
#define BM 64

__device__ __forceinline__ float lrelu(float v){ return v >= 0.f ? v : NEG*v; }

// ---------- prep: N1|N2 = [We_top; We_bot] @ Wl  (per layer) ----------
__global__ void prep1_kernel(const float* __restrict__ We, const float* __restrict__ Wl,
                             float* __restrict__ Ntmp){
  int l = blockIdx.x >> 7;
  int k = blockIdx.x & 127;
  int j = threadIdx.x;          // 0..255
  __shared__ float WeS[2*H];
  if (j < H) WeS[j] = We[(size_t)(l*2*H + k)*H + j];
  else       WeS[j] = We[(size_t)(l*2*H + 128 + k)*H + (j-128)];
  __syncthreads();
  const float* wl = Wl + (size_t)l*H*H;
  int sel = (j >> 7) << 7;      // 0 or 128
  int jj = j & 127;
  float acc = 0.f;
  #pragma unroll 8
  for (int m=0;m<H;m++) acc += WeS[sel + m] * wl[m*H + jj];
  Ntmp[(size_t)(l*H + k)*256 + j] = acc;
}

// ---------- prep: Mcomb = Wg @ [N1|N2] ----------
__global__ void prep2_kernel(const float* __restrict__ Wg, const float* __restrict__ Ntmp,
                             float* __restrict__ Mcomb){
  int l = blockIdx.x >> 7;
  int k = blockIdx.x & 127;
  int j = threadIdx.x;          // 0..255
  __shared__ float WgS[H];
  if (j < H) WgS[j] = Wg[(size_t)(l*H + k)*H + j];
  __syncthreads();
  const float* nt = Ntmp + (size_t)l*H*256;
  float acc = 0.f;
  #pragma unroll 8
  for (int m=0;m<H;m++) acc += WgS[m] * nt[m*256 + j];
  Mcomb[(size_t)(l*H + k)*256 + j] = acc;
}

// ---------- prep: c1 = be@Wl ; c2 = bg@Wl + bl ----------
__global__ void prepc_kernel(const float* __restrict__ be, const float* __restrict__ bg,
                             const float* __restrict__ bl, const float* __restrict__ Wl,
                             float* __restrict__ c1c2){
  int l = blockIdx.x;
  int j = threadIdx.x;          // 0..127
  const float* wl = Wl + (size_t)l*H*H;
  float a1=0.f, a2=0.f;
  for (int m=0;m<H;m++){ float w = wl[m*H + j]; a1 += be[l*H+m]*w; a2 += bg[l*H+m]*w; }
  c1c2[l*2*H + j]     = a1;
  c1c2[l*2*H + H + j] = a2 + bl[l*H + j];
}

// ---------- in-degree count (without self loop; +1 applied later) ----------
__global__ void deg_kernel(const int* __restrict__ ei, int E, int* __restrict__ degI){
  int e = blockIdx.x*blockDim.x + threadIdx.x;
  if (e < E) atomicAdd(&degI[ei[E + e]], 1);
}

// ---------- GEMM: [U|V] = Z @ Mcomb(128x256); epilogue: pre = deg*(U+c1)+c2+V ; store V ----------
__global__ __launch_bounds__(256)
void gemm_kernel(const float* __restrict__ Z, const float* __restrict__ Mc,
                 const float* __restrict__ c1c2, const int* __restrict__ degI,
                 int n, float* __restrict__ pre, float* __restrict__ V){
  __shared__ float As[BM][36];      // [row][k-chunk], padded
  __shared__ float Ms[32][256];
  int brow = blockIdx.x * BM;
  int t = threadIdx.x;
  int tx = t & 31, ty = t >> 5;
  float acc[8][8];
  #pragma unroll
  for(int i=0;i<8;i++)
    #pragma unroll
    for(int j=0;j<8;j++) acc[i][j]=0.f;

  for (int k0=0;k0<H;k0+=32){
    {
      int tw = t & 7, rr = t >> 3;  // rr 0..31
      #pragma unroll
      for (int h=0; h<2; h++){
        int r = rr + h*32;
        int gr = brow + r;
        float4 g = make_float4(0.f,0.f,0.f,0.f);
        if (gr < n) g = *reinterpret_cast<const float4*>(&Z[(size_t)gr*H + k0 + tw*4]);
        *reinterpret_cast<float4*>(&As[r][tw*4]) = g;
      }
      const float* msrc = Mc + (size_t)k0*256;
      #pragma unroll
      for (int u=0;u<8;u++){
        int f = t + 256*u;          // 0..2047
        int kk = f >> 6, j4 = f & 63;
        float4 g = *reinterpret_cast<const float4*>(&msrc[kk*256 + j4*4]);
        *reinterpret_cast<float4*>(&Ms[kk][j4*4]) = g;
      }
    }
    __syncthreads();
    #pragma unroll 4
    for (int kk=0; kk<32; kk++){
      float4 mv0 = *reinterpret_cast<const float4*>(&Ms[kk][tx*4]);
      float4 mv1 = *reinterpret_cast<const float4*>(&Ms[kk][128 + tx*4]);
      float m[8] = {mv0.x,mv0.y,mv0.z,mv0.w, mv1.x,mv1.y,mv1.z,mv1.w};
      float a[8];
      #pragma unroll
      for (int i=0;i<8;i++) a[i] = As[ty*8+i][kk];
      #pragma unroll
      for (int i=0;i<8;i++)
        #pragma unroll
        for (int j=0;j<8;j++)
          acc[i][j] += a[i]*m[j];
    }
    __syncthreads();
  }

  float c1v[4], c2v[4];
  #pragma unroll
  for(int j=0;j<4;j++){ c1v[j] = c1c2[tx*4+j]; c2v[j] = c1c2[H + tx*4+j]; }
  #pragma unroll
  for (int i=0;i<8;i++){
    int gr = brow + ty*8 + i;
    if (gr < n){
      float dg = (float)(degI[gr] + 1);
      float4 pv, vv;
      vv.x = acc[i][4]; vv.y = acc[i][5]; vv.z = acc[i][6]; vv.w = acc[i][7];
      pv.x = dg*(acc[i][0] + c1v[0]) + c2v[0] + vv.x;
      pv.y = dg*(acc[i][1] + c1v[1]) + c2v[1] + vv.y;
      pv.z = dg*(acc[i][2] + c1v[2]) + c2v[2] + vv.z;
      pv.w = dg*(acc[i][3] + c1v[3]) + c2v[3] + vv.w;
      *reinterpret_cast<float4*>(&pre[(size_t)gr*H + tx*4]) = pv;
      *reinterpret_cast<float4*>(&V  [(size_t)gr*H + tx*4]) = vv;
    }
  }
}

// ---------- edge scatter: pre[col] += V[row]  (32 lanes x float4 per edge) ----------
__global__ __launch_bounds__(256)
void scatter_kernel(const int* __restrict__ ei, int E,
                    const float* __restrict__ V, float* __restrict__ pre){
  int idx = blockIdx.x*256 + threadIdx.x;
  int e = idx >> 5;
  int lane = idx & 31;
  if (e >= E) return;
  int r = ei[e], c = ei[E + e];
  float4 v = *reinterpret_cast<const float4*>(&V[(size_t)r*H + lane*4]);
  float* p = &pre[(size_t)c*H + lane*4];
  atomicAdd(p+0, v.x); atomicAdd(p+1, v.y); atomicAdd(p+2, v.z); atomicAdd(p+3, v.w);
}

// ---------- BN stats: per-column sum & sumsq of lrelu(pre) ----------
__global__ __launch_bounds__(256)
void bnstats_kernel(const float* __restrict__ pre, int n, float* __restrict__ bnsum){
  int col  = threadIdx.x & 127;
  int half = threadIdx.x >> 7;
  float s = 0.f, ss = 0.f;
  for (int row = blockIdx.x*2 + half; row < n; row += gridDim.x*2){
    float h = lrelu(pre[(size_t)row*H + col]);
    s += h; ss += h*h;
  }
  __shared__ float sh[2][2][128];
  sh[0][half][col] = s; sh[1][half][col] = ss;
  __syncthreads();
  if (half == 0){
    atomicAdd(&bnsum[col],     sh[0][0][col] + sh[0][1][col]);
    atomicAdd(&bnsum[H + col], sh[1][0][col] + sh[1][1][col]);
  }
}

__global__ void bnfin_kernel(const float* __restrict__ bnsum, float inv_n, float* __restrict__ munrs){
  int c = threadIdx.x;
  float mu  = bnsum[c] * inv_n;
  float var = bnsum[H + c]*inv_n - mu*mu;
  munrs[c]     = mu;
  munrs[H + c] = rsqrtf(fmaxf(var, 0.f) + EPSBN);
}

// ---------- normalize (+ optional pooled accumulation on last layer) ----------
template<int POOL>
__global__ __launch_bounds__(256)
void norm_kernel(const float* __restrict__ pre, const float* __restrict__ munrs,
                 const float* __restrict__ gamma, const float* __restrict__ beta,
                 int n, float* __restrict__ zout,
                 const int* __restrict__ batch, float* __restrict__ pooled){
  int idx = blockIdx.x*256 + threadIdx.x;
  int total = n*(H/4);
  if (idx >= total) return;
  int row = idx >> 5;
  int c4  = (idx & 31)*4;
  float4 p = *reinterpret_cast<const float4*>(&pre[(size_t)row*H + c4]);
  float4 o;
  o.x = gamma[c4+0]*(lrelu(p.x) - munrs[c4+0])*munrs[H+c4+0] + beta[c4+0];
  o.y = gamma[c4+1]*(lrelu(p.y) - munrs[c4+1])*munrs[H+c4+1] + beta[c4+1];
  o.z = gamma[c4+2]*(lrelu(p.z) - munrs[c4+2])*munrs[H+c4+2] + beta[c4+2];
  o.w = gamma[c4+3]*(lrelu(p.w) - munrs[c4+3])*munrs[H+c4+3] + beta[c4+3];
  *reinterpret_cast<float4*>(&zout[(size_t)row*H + c4]) = o;
  if (POOL){
    int b = batch[row];
    float* pp = &pooled[(size_t)b*H + c4];
    atomicAdd(pp+0, o.x); atomicAdd(pp+1, o.y); atomicAdd(pp+2, o.z); atomicAdd(pp+3, o.w);
  }
}

__global__ void cnt_kernel(const int* __restrict__ batch, int n, int* __restrict__ cntI){
  int i = blockIdx.x*256 + threadIdx.x;
  if (i < n) atomicAdd(&cntI[batch[i]], 1);
}

// ---------- final MLP head: one block per graph ----------
__global__ __launch_bounds__(128)
void head_kernel(const float* __restrict__ pooled, const int* __restrict__ cntI,
                 const float* __restrict__ Wf1, const float* __restrict__ bf1,
                 const float* __restrict__ Wf2, const float* __restrict__ bf2,
                 const float* __restrict__ Wf3, const float* __restrict__ bf3,
                 float* __restrict__ out){
  int g = blockIdx.x;
  int c = threadIdx.x;
  __shared__ float pm[128], h1[128], h2[64];
  float cf = fmaxf((float)cntI[g], 1.f);
  pm[c] = pooled[(size_t)g*H + c] / cf;
  __syncthreads();
  float a = bf1[c];
  for (int k=0;k<H;k++) a += pm[k]*Wf1[k*H + c];
  h1[c] = lrelu(a);
  __syncthreads();
  if (c < 64){
    float b = bf2[c];
    for (int k=0;k<H;k++) b += h1[k]*Wf2[k*64 + c];
    h2[c] = lrelu(b);
  }
  __syncthreads();
  if (c < 2){
    float o = bf3[c];
    for (int k=0;k<64;k++) o += h2[k]*Wf3[k*2 + c];
    out[g*2 + c] = o;
  }
}

extern "C" void kernel_launch(void* const* d_in, const int* in_sizes, int n_in,
                              void* d_out, int out_size, void* d_ws, size_t ws_size,
                              hipStream_t stream){
  const float* x     = (const float*)d_in[0];
  const int*   ei    = (const int*)d_in[1];
  const int*   batch = (const int*)d_in[3];
  const float* Wg    = (const float*)d_in[4];
  const float* bg    = (const float*)d_in[5];
  const float* We    = (const float*)d_in[6];
  const float* be    = (const float*)d_in[7];
  const float* Wl    = (const float*)d_in[8];
  const float* bl    = (const float*)d_in[9];
  const float* gamma = (const float*)d_in[10];
  const float* beta  = (const float*)d_in[11];
  const float* Wf1   = (const float*)d_in[12];
  const float* bf1   = (const float*)d_in[13];
  const float* Wf2   = (const float*)d_in[14];
  const float* bf2   = (const float*)d_in[15];
  const float* Wf3   = (const float*)d_in[16];
  const float* bf3   = (const float*)d_in[17];
  float* out = (float*)d_out;

  int n = in_sizes[0] / H;   // 50000
  int E = in_sizes[1] / 2;   // 800000
  int B = out_size / 2;      // 50

  char* ws = (char*)d_ws;
  size_t off = 0;
  auto alloc = [&](size_t bytes)->void*{ void* p = ws + off; off += (bytes + 255) & ~255ULL; return p; };
  float* pre   = (float*)alloc((size_t)n*H*4);
  float* V     = (float*)alloc((size_t)n*H*4);
  float* zC    = (float*)alloc((size_t)n*H*4);
  float* Mcomb = (float*)alloc((size_t)3*H*256*4);
  float* Ntmp  = (float*)alloc((size_t)3*H*256*4);
  float* c1c2  = (float*)alloc(3*2*H*4);
  float* munrs = (float*)alloc(3*2*H*4);
  char* zbase = ws + off;                 // ---- zeroed region starts ----
  float* bnsum  = (float*)alloc(3*2*H*4);
  int*   degI   = (int*)alloc((size_t)n*4);
  float* pooled = (float*)alloc((size_t)B*H*4);
  int*   cntI   = (int*)alloc((size_t)B*4);
  size_t zbytes = (size_t)((ws + off) - zbase);
  hipMemsetAsync(zbase, 0, zbytes, stream);

  prep1_kernel<<<3*H, 256, 0, stream>>>(We, Wl, Ntmp);
  prep2_kernel<<<3*H, 256, 0, stream>>>(Wg, Ntmp, Mcomb);
  prepc_kernel<<<3, 128, 0, stream>>>(be, bg, bl, Wl, c1c2);
  deg_kernel<<<(E+255)/256, 256, 0, stream>>>(ei, E, degI);

  const float* z = x;
  int gblocks = (n + BM - 1)/BM;
  for (int l=0; l<3; l++){
    gemm_kernel<<<gblocks, 256, 0, stream>>>(z, Mcomb + (size_t)l*H*256, c1c2 + l*2*H, degI, n, pre, V);
    scatter_kernel<<<(E*32 + 255)/256, 256, 0, stream>>>(ei, E, V, pre);
    bnstats_kernel<<<512, 256, 0, stream>>>(pre, n, bnsum + l*2*H);
    bnfin_kernel<<<1, 128, 0, stream>>>(bnsum + l*2*H, 1.f/(float)n, munrs + l*2*H);
    if (l < 2)
      norm_kernel<0><<<(n*32+255)/256, 256, 0, stream>>>(pre, munrs + l*2*H, gamma + l*H, beta + l*H, n, zC, nullptr, nullptr);
    else
      norm_kernel<1><<<(n*32+255)/256, 256, 0, stream>>>(pre, munrs + l*2*H, gamma + l*H, beta + l*H, n, zC, batch, pooled);
    z = zC;
  }
  cnt_kernel<<<(n+255)/256, 256, 0, stream>>>(batch, n, cntI);
  head_kernel<<<B, 128, 0, stream>>>(pooled, cntI, Wf1, bf1, Wf2, bf2, Wf3, bf3, out);
}

// Round 2
// 1057.607 us; speedup vs baseline: 4.5561x; 4.5561x over previous
//
#include <hip/hip_runtime.h>

#define H 128
#define NEG 0.2f
#define EPSBN 1e-5f
#define BM 64

__device__ __forceinline__ float lrelu(float v){ return v >= 0.f ? v : NEG*v; }

// ---------- prep: N1|N2 = [We_top; We_bot] @ Wl  (per layer) ----------
__global__ void prep1_kernel(const float* __restrict__ We, const float* __restrict__ Wl,
                             float* __restrict__ Ntmp){
  int l = blockIdx.x >> 7;
  int k = blockIdx.x & 127;
  int j = threadIdx.x;          // 0..255
  __shared__ float WeS[2*H];
  if (j < H) WeS[j] = We[(size_t)(l*2*H + k)*H + j];
  else       WeS[j] = We[(size_t)(l*2*H + 128 + k)*H + (j-128)];
  __syncthreads();
  const float* wl = Wl + (size_t)l*H*H;
  int sel = (j >> 7) << 7;      // 0 or 128
  int jj = j & 127;
  float acc = 0.f;
  #pragma unroll 8
  for (int m=0;m<H;m++) acc += WeS[sel + m] * wl[m*H + jj];
  Ntmp[(size_t)(l*H + k)*256 + j] = acc;
}

// ---------- prep: Mcomb = Wg @ [N1|N2] ----------
__global__ void prep2_kernel(const float* __restrict__ Wg, const float* __restrict__ Ntmp,
                             float* __restrict__ Mcomb){
  int l = blockIdx.x >> 7;
  int k = blockIdx.x & 127;
  int j = threadIdx.x;          // 0..255
  __shared__ float WgS[H];
  if (j < H) WgS[j] = Wg[(size_t)(l*H + k)*H + j];
  __syncthreads();
  const float* nt = Ntmp + (size_t)l*H*256;
  float acc = 0.f;
  #pragma unroll 8
  for (int m=0;m<H;m++) acc += WgS[m] * nt[m*256 + j];
  Mcomb[(size_t)(l*H + k)*256 + j] = acc;
}

// ---------- prep: c1 = be@Wl ; c2 = bg@Wl + bl ----------
__global__ void prepc_kernel(const float* __restrict__ be, const float* __restrict__ bg,
                             const float* __restrict__ bl, const float* __restrict__ Wl,
                             float* __restrict__ c1c2){
  int l = blockIdx.x;
  int j = threadIdx.x;          // 0..127
  const float* wl = Wl + (size_t)l*H*H;
  float a1=0.f, a2=0.f;
  for (int m=0;m<H;m++){ float w = wl[m*H + j]; a1 += be[l*H+m]*w; a2 += bg[l*H+m]*w; }
  c1c2[l*2*H + j]     = a1;
  c1c2[l*2*H + H + j] = a2 + bl[l*H + j];
}

// ---------- in-degree count (without self loop; +1 applied later) ----------
__global__ void deg_kernel(const int* __restrict__ ei, int E, int* __restrict__ degI){
  int e = blockIdx.x*blockDim.x + threadIdx.x;
  if (e < E) atomicAdd(&degI[ei[E + e]], 1);
}

// ---------- CSR build: block-wise inclusive scan of degrees ----------
__global__ void scan1_kernel(const int* __restrict__ degI, int n,
                             int* __restrict__ incl, int* __restrict__ bsum){
  int i = blockIdx.x*256 + threadIdx.x;
  __shared__ int sh[256];
  int v = (i < n) ? degI[i] : 0;
  sh[threadIdx.x] = v;
  __syncthreads();
  for (int ofs=1; ofs<256; ofs<<=1){
    int t = (threadIdx.x >= ofs) ? sh[threadIdx.x - ofs] : 0;
    __syncthreads();
    sh[threadIdx.x] += t;
    __syncthreads();
  }
  if (i < n) incl[i] = sh[threadIdx.x];
  if (threadIdx.x == 255) bsum[blockIdx.x] = sh[255];
}

__global__ void scan2_kernel(int* __restrict__ bsum, int nb){
  __shared__ int sh[256];
  int v = (threadIdx.x < nb) ? bsum[threadIdx.x] : 0;
  sh[threadIdx.x] = v;
  __syncthreads();
  for (int ofs=1; ofs<256; ofs<<=1){
    int t = (threadIdx.x >= ofs) ? sh[threadIdx.x - ofs] : 0;
    __syncthreads();
    sh[threadIdx.x] += t;
    __syncthreads();
  }
  if (threadIdx.x < nb) bsum[threadIdx.x] = sh[threadIdx.x] - v;  // exclusive
}

__global__ void scan3_kernel(const int* __restrict__ incl, const int* __restrict__ degI,
                             const int* __restrict__ bexcl, int n, int E,
                             int* __restrict__ rowptr, int* __restrict__ cursor){
  int i = blockIdx.x*256 + threadIdx.x;
  if (i < n){
    int start = incl[i] - degI[i] + bexcl[blockIdx.x];
    rowptr[i] = start;
    cursor[i] = start;
    if (i == n-1) rowptr[n] = E;
  }
}

__global__ void fill_kernel(const int* __restrict__ ei, int E,
                            int* __restrict__ cursor, int* __restrict__ csr_src){
  int e = blockIdx.x*256 + threadIdx.x;
  if (e < E){
    int c = ei[E + e];
    int pos = atomicAdd(&cursor[c], 1);
    csr_src[pos] = ei[e];
  }
}

// ---------- GEMM: [U|V] = Z @ Mcomb(128x256); epilogue: pre = deg*(U+c1)+c2+V ; store V ----------
__global__ __launch_bounds__(256)
void gemm_kernel(const float* __restrict__ Z, const float* __restrict__ Mc,
                 const float* __restrict__ c1c2, const int* __restrict__ degI,
                 int n, float* __restrict__ pre, float* __restrict__ V){
  __shared__ float As[BM][36];      // [row][k-chunk], padded
  __shared__ float Ms[32][256];
  int brow = blockIdx.x * BM;
  int t = threadIdx.x;
  int tx = t & 31, ty = t >> 5;
  float acc[8][8];
  #pragma unroll
  for(int i=0;i<8;i++)
    #pragma unroll
    for(int j=0;j<8;j++) acc[i][j]=0.f;

  for (int k0=0;k0<H;k0+=32){
    {
      int tw = t & 7, rr = t >> 3;  // rr 0..31
      #pragma unroll
      for (int h=0; h<2; h++){
        int r = rr + h*32;
        int gr = brow + r;
        float4 g = make_float4(0.f,0.f,0.f,0.f);
        if (gr < n) g = *reinterpret_cast<const float4*>(&Z[(size_t)gr*H + k0 + tw*4]);
        *reinterpret_cast<float4*>(&As[r][tw*4]) = g;
      }
      const float* msrc = Mc + (size_t)k0*256;
      #pragma unroll
      for (int u=0;u<8;u++){
        int f = t + 256*u;          // 0..2047
        int kk = f >> 6, j4 = f & 63;
        float4 g = *reinterpret_cast<const float4*>(&msrc[kk*256 + j4*4]);
        *reinterpret_cast<float4*>(&Ms[kk][j4*4]) = g;
      }
    }
    __syncthreads();
    #pragma unroll 4
    for (int kk=0; kk<32; kk++){
      float4 mv0 = *reinterpret_cast<const float4*>(&Ms[kk][tx*4]);
      float4 mv1 = *reinterpret_cast<const float4*>(&Ms[kk][128 + tx*4]);
      float m[8] = {mv0.x,mv0.y,mv0.z,mv0.w, mv1.x,mv1.y,mv1.z,mv1.w};
      float a[8];
      #pragma unroll
      for (int i=0;i<8;i++) a[i] = As[ty*8+i][kk];
      #pragma unroll
      for (int i=0;i<8;i++)
        #pragma unroll
        for (int j=0;j<8;j++)
          acc[i][j] += a[i]*m[j];
    }
    __syncthreads();
  }

  float c1v[4], c2v[4];
  #pragma unroll
  for(int j=0;j<4;j++){ c1v[j] = c1c2[tx*4+j]; c2v[j] = c1c2[H + tx*4+j]; }
  #pragma unroll
  for (int i=0;i<8;i++){
    int gr = brow + ty*8 + i;
    if (gr < n){
      float dg = (float)(degI[gr] + 1);
      float4 pv, vv;
      vv.x = acc[i][4]; vv.y = acc[i][5]; vv.z = acc[i][6]; vv.w = acc[i][7];
      pv.x = dg*(acc[i][0] + c1v[0]) + c2v[0] + vv.x;
      pv.y = dg*(acc[i][1] + c1v[1]) + c2v[1] + vv.y;
      pv.z = dg*(acc[i][2] + c1v[2]) + c2v[2] + vv.z;
      pv.w = dg*(acc[i][3] + c1v[3]) + c2v[3] + vv.w;
      *reinterpret_cast<float4*>(&pre[(size_t)gr*H + tx*4]) = pv;
      *reinterpret_cast<float4*>(&V  [(size_t)gr*H + tx*4]) = vv;
    }
  }
}

// ---------- CSR aggregation: pre[i] += sum_{e in in(i)} V[src_e]  (1 wave/node) ----------
__global__ __launch_bounds__(256)
void agg_kernel(const int* __restrict__ rowptr, const int* __restrict__ csr_src,
                const float* __restrict__ V, float* __restrict__ pre, int n){
  int node = blockIdx.x*4 + (threadIdx.x >> 6);
  if (node >= n) return;
  int lane = threadIdx.x & 63;
  int p  = rowptr[node];
  int pe = rowptr[node+1];
  const float* Vb = V + lane*2;
  float ax = 0.f, ay = 0.f;
  for (; p+4 <= pe; p+=4){
    int s0 = csr_src[p], s1 = csr_src[p+1], s2 = csr_src[p+2], s3 = csr_src[p+3];
    float2 v0 = *reinterpret_cast<const float2*>(&Vb[(size_t)s0*H]);
    float2 v1 = *reinterpret_cast<const float2*>(&Vb[(size_t)s1*H]);
    float2 v2 = *reinterpret_cast<const float2*>(&Vb[(size_t)s2*H]);
    float2 v3 = *reinterpret_cast<const float2*>(&Vb[(size_t)s3*H]);
    ax += v0.x + v1.x + v2.x + v3.x;
    ay += v0.y + v1.y + v2.y + v3.y;
  }
  for (; p < pe; p++){
    int s = csr_src[p];
    float2 v = *reinterpret_cast<const float2*>(&Vb[(size_t)s*H]);
    ax += v.x; ay += v.y;
  }
  float2* pp = reinterpret_cast<float2*>(&pre[(size_t)node*H + lane*2]);
  float2 pr = *pp;
  pr.x += ax; pr.y += ay;
  *pp = pr;
}

// ---------- BN stats: per-column sum & sumsq of lrelu(pre) ----------
__global__ __launch_bounds__(256)
void bnstats_kernel(const float* __restrict__ pre, int n, float* __restrict__ bnsum){
  int col  = threadIdx.x & 127;
  int half = threadIdx.x >> 7;
  float s = 0.f, ss = 0.f;
  for (int row = blockIdx.x*2 + half; row < n; row += gridDim.x*2){
    float h = lrelu(pre[(size_t)row*H + col]);
    s += h; ss += h*h;
  }
  __shared__ float sh[2][2][128];
  sh[0][half][col] = s; sh[1][half][col] = ss;
  __syncthreads();
  if (half == 0){
    atomicAdd(&bnsum[col],     sh[0][0][col] + sh[0][1][col]);
    atomicAdd(&bnsum[H + col], sh[1][0][col] + sh[1][1][col]);
  }
}

__global__ void bnfin_kernel(const float* __restrict__ bnsum, float inv_n, float* __restrict__ munrs){
  int c = threadIdx.x;
  float mu  = bnsum[c] * inv_n;
  float var = bnsum[H + c]*inv_n - mu*mu;
  munrs[c]     = mu;
  munrs[H + c] = rsqrtf(fmaxf(var, 0.f) + EPSBN);
}

// ---------- normalize (+ optional pooled accumulation on last layer) ----------
template<int POOL>
__global__ __launch_bounds__(256)
void norm_kernel(const float* __restrict__ pre, const float* __restrict__ munrs,
                 const float* __restrict__ gamma, const float* __restrict__ beta,
                 int n, float* __restrict__ zout,
                 const int* __restrict__ batch, float* __restrict__ pooled){
  int idx = blockIdx.x*256 + threadIdx.x;
  int total = n*(H/4);
  if (idx >= total) return;
  int row = idx >> 5;
  int c4  = (idx & 31)*4;
  float4 p = *reinterpret_cast<const float4*>(&pre[(size_t)row*H + c4]);
  float4 o;
  o.x = gamma[c4+0]*(lrelu(p.x) - munrs[c4+0])*munrs[H+c4+0] + beta[c4+0];
  o.y = gamma[c4+1]*(lrelu(p.y) - munrs[c4+1])*munrs[H+c4+1] + beta[c4+1];
  o.z = gamma[c4+2]*(lrelu(p.z) - munrs[c4+2])*munrs[H+c4+2] + beta[c4+2];
  o.w = gamma[c4+3]*(lrelu(p.w) - munrs[c4+3])*munrs[H+c4+3] + beta[c4+3];
  *reinterpret_cast<float4*>(&zout[(size_t)row*H + c4]) = o;
  if (POOL){
    int b = batch[row];
    float* pp = &pooled[(size_t)b*H + c4];
    atomicAdd(pp+0, o.x); atomicAdd(pp+1, o.y); atomicAdd(pp+2, o.z); atomicAdd(pp+3, o.w);
  }
}

__global__ void cnt_kernel(const int* __restrict__ batch, int n, int* __restrict__ cntI){
  int i = blockIdx.x*256 + threadIdx.x;
  if (i < n) atomicAdd(&cntI[batch[i]], 1);
}

// ---------- final MLP head: one block per graph ----------
__global__ __launch_bounds__(128)
void head_kernel(const float* __restrict__ pooled, const int* __restrict__ cntI,
                 const float* __restrict__ Wf1, const float* __restrict__ bf1,
                 const float* __restrict__ Wf2, const float* __restrict__ bf2,
                 const float* __restrict__ Wf3, const float* __restrict__ bf3,
                 float* __restrict__ out){
  int g = blockIdx.x;
  int c = threadIdx.x;
  __shared__ float pm[128], h1[128], h2[64];
  float cf = fmaxf((float)cntI[g], 1.f);
  pm[c] = pooled[(size_t)g*H + c] / cf;
  __syncthreads();
  float a = bf1[c];
  for (int k=0;k<H;k++) a += pm[k]*Wf1[k*H + c];
  h1[c] = lrelu(a);
  __syncthreads();
  if (c < 64){
    float b = bf2[c];
    for (int k=0;k<H;k++) b += h1[k]*Wf2[k*64 + c];
    h2[c] = lrelu(b);
  }
  __syncthreads();
  if (c < 2){
    float o = bf3[c];
    for (int k=0;k<64;k++) o += h2[k]*Wf3[k*2 + c];
    out[g*2 + c] = o;
  }
}

extern "C" void kernel_launch(void* const* d_in, const int* in_sizes, int n_in,
                              void* d_out, int out_size, void* d_ws, size_t ws_size,
                              hipStream_t stream){
  const float* x     = (const float*)d_in[0];
  const int*   ei    = (const int*)d_in[1];
  const int*   batch = (const int*)d_in[3];
  const float* Wg    = (const float*)d_in[4];
  const float* bg    = (const float*)d_in[5];
  const float* We    = (const float*)d_in[6];
  const float* be    = (const float*)d_in[7];
  const float* Wl    = (const float*)d_in[8];
  const float* bl    = (const float*)d_in[9];
  const float* gamma = (const float*)d_in[10];
  const float* beta  = (const float*)d_in[11];
  const float* Wf1   = (const float*)d_in[12];
  const float* bf1   = (const float*)d_in[13];
  const float* Wf2   = (const float*)d_in[14];
  const float* bf2   = (const float*)d_in[15];
  const float* Wf3   = (const float*)d_in[16];
  const float* bf3   = (const float*)d_in[17];
  float* out = (float*)d_out;

  int n = in_sizes[0] / H;   // 50000
  int E = in_sizes[1] / 2;   // 800000
  int B = out_size / 2;      // 50

  char* ws = (char*)d_ws;
  size_t off = 0;
  auto alloc = [&](size_t bytes)->void*{ void* p = ws + off; off += (bytes + 255) & ~255ULL; return p; };
  float* pre    = (float*)alloc((size_t)n*H*4);
  float* V      = (float*)alloc((size_t)n*H*4);
  float* zC     = (float*)alloc((size_t)n*H*4);
  float* Mcomb  = (float*)alloc((size_t)3*H*256*4);
  float* Ntmp   = (float*)alloc((size_t)3*H*256*4);
  float* c1c2   = (float*)alloc(3*2*H*4);
  float* munrs  = (float*)alloc(3*2*H*4);
  int*   incl   = (int*)alloc((size_t)n*4);
  int*   bsum   = (int*)alloc(256*4);
  int*   rowptr = (int*)alloc((size_t)(n+1)*4);
  int*   cursor = (int*)alloc((size_t)n*4);
  int*   csr_src= (int*)alloc((size_t)E*4);
  char* zbase = ws + off;                 // ---- zeroed region starts ----
  float* bnsum  = (float*)alloc(3*2*H*4);
  int*   degI   = (int*)alloc((size_t)n*4);
  float* pooled = (float*)alloc((size_t)B*H*4);
  int*   cntI   = (int*)alloc((size_t)B*4);
  size_t zbytes = (size_t)((ws + off) - zbase);
  hipMemsetAsync(zbase, 0, zbytes, stream);

  prep1_kernel<<<3*H, 256, 0, stream>>>(We, Wl, Ntmp);
  prep2_kernel<<<3*H, 256, 0, stream>>>(Wg, Ntmp, Mcomb);
  prepc_kernel<<<3, 128, 0, stream>>>(be, bg, bl, Wl, c1c2);
  deg_kernel<<<(E+255)/256, 256, 0, stream>>>(ei, E, degI);

  int nb = (n + 255)/256;
  scan1_kernel<<<nb, 256, 0, stream>>>(degI, n, incl, bsum);
  scan2_kernel<<<1, 256, 0, stream>>>(bsum, nb);
  scan3_kernel<<<nb, 256, 0, stream>>>(incl, degI, bsum, n, E, rowptr, cursor);
  fill_kernel<<<(E+255)/256, 256, 0, stream>>>(ei, E, cursor, csr_src);

  const float* z = x;
  int gblocks = (n + BM - 1)/BM;
  for (int l=0; l<3; l++){
    gemm_kernel<<<gblocks, 256, 0, stream>>>(z, Mcomb + (size_t)l*H*256, c1c2 + l*2*H, degI, n, pre, V);
    agg_kernel<<<(n+3)/4, 256, 0, stream>>>(rowptr, csr_src, V, pre, n);
    bnstats_kernel<<<512, 256, 0, stream>>>(pre, n, bnsum + l*2*H);
    bnfin_kernel<<<1, 128, 0, stream>>>(bnsum + l*2*H, 1.f/(float)n, munrs + l*2*H);
    if (l < 2)
      norm_kernel<0><<<(n*32+255)/256, 256, 0, stream>>>(pre, munrs + l*2*H, gamma + l*H, beta + l*H, n, zC, nullptr, nullptr);
    else
      norm_kernel<1><<<(n*32+255)/256, 256, 0, stream>>>(pre, munrs + l*2*H, gamma + l*H, beta + l*H, n, zC, batch, pooled);
    z = zC;
  }
  cnt_kernel<<<(n+255)/256, 256, 0, stream>>>(batch, n, cntI);
  head_kernel<<<B, 128, 0, stream>>>(pooled, cntI, Wf1, bf1, Wf2, bf2, Wf3, bf3, out);
}

// Round 3
// 569.598 us; speedup vs baseline: 8.4597x; 1.8568x over previous
//
#include <hip/hip_runtime.h>

#define H 128
#define NEG 0.2f
#define EPSBN 1e-5f
#define BM 64

__device__ __forceinline__ float lrelu(float v){ return v >= 0.f ? v : NEG*v; }

// ---------- prep: N1|N2 = [We_top; We_bot] @ Wl  (per layer) ----------
__global__ void prep1_kernel(const float* __restrict__ We, const float* __restrict__ Wl,
                             float* __restrict__ Ntmp){
  int l = blockIdx.x >> 7;
  int k = blockIdx.x & 127;
  int j = threadIdx.x;          // 0..255
  __shared__ float WeS[2*H];
  if (j < H) WeS[j] = We[(size_t)(l*2*H + k)*H + j];
  else       WeS[j] = We[(size_t)(l*2*H + 128 + k)*H + (j-128)];
  __syncthreads();
  const float* wl = Wl + (size_t)l*H*H;
  int sel = (j >> 7) << 7;      // 0 or 128
  int jj = j & 127;
  float acc = 0.f;
  #pragma unroll 8
  for (int m=0;m<H;m++) acc += WeS[sel + m] * wl[m*H + jj];
  Ntmp[(size_t)(l*H + k)*256 + j] = acc;
}

// ---------- prep: Mcomb = Wg @ [N1|N2] ----------
__global__ void prep2_kernel(const float* __restrict__ Wg, const float* __restrict__ Ntmp,
                             float* __restrict__ Mcomb){
  int l = blockIdx.x >> 7;
  int k = blockIdx.x & 127;
  int j = threadIdx.x;          // 0..255
  __shared__ float WgS[H];
  if (j < H) WgS[j] = Wg[(size_t)(l*H + k)*H + j];
  __syncthreads();
  const float* nt = Ntmp + (size_t)l*H*256;
  float acc = 0.f;
  #pragma unroll 8
  for (int m=0;m<H;m++) acc += WgS[m] * nt[m*256 + j];
  Mcomb[(size_t)(l*H + k)*256 + j] = acc;
}

// ---------- prep: c1 = be@Wl ; c2 = bg@Wl + bl ----------
__global__ void prepc_kernel(const float* __restrict__ be, const float* __restrict__ bg,
                             const float* __restrict__ bl, const float* __restrict__ Wl,
                             float* __restrict__ c1c2){
  int l = blockIdx.x;
  int j = threadIdx.x;          // 0..127
  const float* wl = Wl + (size_t)l*H*H;
  float a1=0.f, a2=0.f;
  for (int m=0;m<H;m++){ float w = wl[m*H + j]; a1 += be[l*H+m]*w; a2 += bg[l*H+m]*w; }
  c1c2[l*2*H + j]     = a1;
  c1c2[l*2*H + H + j] = a2 + bl[l*H + j];
}

// ---------- in-degree count (without self loop; +1 applied later) ----------
__global__ void deg_kernel(const int* __restrict__ ei, int E, int* __restrict__ degI){
  int e = blockIdx.x*blockDim.x + threadIdx.x;
  if (e < E) atomicAdd(&degI[ei[E + e]], 1);
}

// ---------- CSR build: block-wise inclusive scan of degrees ----------
__global__ void scan1_kernel(const int* __restrict__ degI, int n,
                             int* __restrict__ incl, int* __restrict__ bsum){
  int i = blockIdx.x*256 + threadIdx.x;
  __shared__ int sh[256];
  int v = (i < n) ? degI[i] : 0;
  sh[threadIdx.x] = v;
  __syncthreads();
  for (int ofs=1; ofs<256; ofs<<=1){
    int t = (threadIdx.x >= ofs) ? sh[threadIdx.x - ofs] : 0;
    __syncthreads();
    sh[threadIdx.x] += t;
    __syncthreads();
  }
  if (i < n) incl[i] = sh[threadIdx.x];
  if (threadIdx.x == 255) bsum[blockIdx.x] = sh[255];
}

__global__ void scan2_kernel(int* __restrict__ bsum, int nb){
  __shared__ int sh[256];
  int v = (threadIdx.x < nb) ? bsum[threadIdx.x] : 0;
  sh[threadIdx.x] = v;
  __syncthreads();
  for (int ofs=1; ofs<256; ofs<<=1){
    int t = (threadIdx.x >= ofs) ? sh[threadIdx.x - ofs] : 0;
    __syncthreads();
    sh[threadIdx.x] += t;
    __syncthreads();
  }
  if (threadIdx.x < nb) bsum[threadIdx.x] = sh[threadIdx.x] - v;  // exclusive
}

__global__ void scan3_kernel(const int* __restrict__ incl, const int* __restrict__ degI,
                             const int* __restrict__ bexcl, int n, int E,
                             int* __restrict__ rowptr, int* __restrict__ cursor){
  int i = blockIdx.x*256 + threadIdx.x;
  if (i < n){
    int start = incl[i] - degI[i] + bexcl[blockIdx.x];
    rowptr[i] = start;
    cursor[i] = start;
    if (i == n-1) rowptr[n] = E;
  }
}

__global__ void fill_kernel(const int* __restrict__ ei, int E,
                            int* __restrict__ cursor, int* __restrict__ csr_src){
  int e = blockIdx.x*256 + threadIdx.x;
  if (e < E){
    int c = ei[E + e];
    int pos = atomicAdd(&cursor[c], 1);
    csr_src[pos] = ei[e];
  }
}

// ---------- graph boundary offsets from sorted batch ----------
__global__ void gofs_kernel(const int* __restrict__ batch, int n, int B, int* __restrict__ gofs){
  int i = blockIdx.x*256 + threadIdx.x;
  if (i >= n) return;
  if (i == 0){
    int b0 = batch[0];
    for (int g=0; g<=b0; g++) gofs[g] = 0;
  } else {
    int bp = batch[i-1], bc = batch[i];
    for (int g=bp+1; g<=bc; g++) gofs[g] = i;
  }
  if (i == n-1){
    int bl = batch[n-1];
    for (int g=bl+1; g<=B; g++) gofs[g] = n;
  }
}

// ---------- GEMM: [U|V] = A @ Mcomb(128x256); A = Zin (XF=0) or lrelu(Zin)*sc+sh (XF=1) ----------
// epilogue: pre = deg*(U+c1)+c2+V ; store V
template<int XF>
__global__ __launch_bounds__(256)
void gemm_kernel(const float* __restrict__ Zin, const float* __restrict__ bnp,
                 const float* __restrict__ Mc,
                 const float* __restrict__ c1c2, const int* __restrict__ degI,
                 int n, float* __restrict__ pre, float* __restrict__ V){
  __shared__ float As[BM][36];      // [row][k-chunk], padded
  __shared__ float Ms[32][256];
  int brow = blockIdx.x * BM;
  int t = threadIdx.x;
  int tx = t & 31, ty = t >> 5;
  float acc[8][8];
  #pragma unroll
  for(int i=0;i<8;i++)
    #pragma unroll
    for(int j=0;j<8;j++) acc[i][j]=0.f;

  for (int k0=0;k0<H;k0+=32){
    {
      int tw = t & 7, rr = t >> 3;  // rr 0..31
      float4 sc4, sh4;
      if (XF){
        sc4 = *reinterpret_cast<const float4*>(&bnp[k0 + tw*4]);
        sh4 = *reinterpret_cast<const float4*>(&bnp[H + k0 + tw*4]);
      }
      #pragma unroll
      for (int h=0; h<2; h++){
        int r = rr + h*32;
        int gr = brow + r;
        float4 g = make_float4(0.f,0.f,0.f,0.f);
        if (gr < n) g = *reinterpret_cast<const float4*>(&Zin[(size_t)gr*H + k0 + tw*4]);
        if (XF){
          g.x = lrelu(g.x)*sc4.x + sh4.x;
          g.y = lrelu(g.y)*sc4.y + sh4.y;
          g.z = lrelu(g.z)*sc4.z + sh4.z;
          g.w = lrelu(g.w)*sc4.w + sh4.w;
        }
        *reinterpret_cast<float4*>(&As[r][tw*4]) = g;
      }
      const float* msrc = Mc + (size_t)k0*256;
      #pragma unroll
      for (int u=0;u<8;u++){
        int f = t + 256*u;          // 0..2047
        int kk = f >> 6, j4 = f & 63;
        float4 g = *reinterpret_cast<const float4*>(&msrc[kk*256 + j4*4]);
        *reinterpret_cast<float4*>(&Ms[kk][j4*4]) = g;
      }
    }
    __syncthreads();
    #pragma unroll 4
    for (int kk=0; kk<32; kk++){
      float4 mv0 = *reinterpret_cast<const float4*>(&Ms[kk][tx*4]);
      float4 mv1 = *reinterpret_cast<const float4*>(&Ms[kk][128 + tx*4]);
      float m[8] = {mv0.x,mv0.y,mv0.z,mv0.w, mv1.x,mv1.y,mv1.z,mv1.w};
      float a[8];
      #pragma unroll
      for (int i=0;i<8;i++) a[i] = As[ty*8+i][kk];
      #pragma unroll
      for (int i=0;i<8;i++)
        #pragma unroll
        for (int j=0;j<8;j++)
          acc[i][j] += a[i]*m[j];
    }
    __syncthreads();
  }

  float c1v[4], c2v[4];
  #pragma unroll
  for(int j=0;j<4;j++){ c1v[j] = c1c2[tx*4+j]; c2v[j] = c1c2[H + tx*4+j]; }
  #pragma unroll
  for (int i=0;i<8;i++){
    int gr = brow + ty*8 + i;
    if (gr < n){
      float dg = (float)(degI[gr] + 1);
      float4 pv, vv;
      vv.x = acc[i][4]; vv.y = acc[i][5]; vv.z = acc[i][6]; vv.w = acc[i][7];
      pv.x = dg*(acc[i][0] + c1v[0]) + c2v[0] + vv.x;
      pv.y = dg*(acc[i][1] + c1v[1]) + c2v[1] + vv.y;
      pv.z = dg*(acc[i][2] + c1v[2]) + c2v[2] + vv.z;
      pv.w = dg*(acc[i][3] + c1v[3]) + c2v[3] + vv.w;
      *reinterpret_cast<float4*>(&pre[(size_t)gr*H + tx*4]) = pv;
      *reinterpret_cast<float4*>(&V  [(size_t)gr*H + tx*4]) = vv;
    }
  }
}

// ---------- CSR aggregation: pre[i] += sum_{e in in(i)} V[src_e]  (1 wave/node) ----------
__global__ __launch_bounds__(256)
void agg_kernel(const int* __restrict__ rowptr, const int* __restrict__ csr_src,
                const float* __restrict__ V, float* __restrict__ pre, int n){
  int node = blockIdx.x*4 + (threadIdx.x >> 6);
  if (node >= n) return;
  int lane = threadIdx.x & 63;
  int p  = rowptr[node];
  int pe = rowptr[node+1];
  const float* Vb = V + lane*2;
  float ax = 0.f, ay = 0.f;
  for (; p+4 <= pe; p+=4){
    int s0 = csr_src[p], s1 = csr_src[p+1], s2 = csr_src[p+2], s3 = csr_src[p+3];
    float2 v0 = *reinterpret_cast<const float2*>(&Vb[(size_t)s0*H]);
    float2 v1 = *reinterpret_cast<const float2*>(&Vb[(size_t)s1*H]);
    float2 v2 = *reinterpret_cast<const float2*>(&Vb[(size_t)s2*H]);
    float2 v3 = *reinterpret_cast<const float2*>(&Vb[(size_t)s3*H]);
    ax += v0.x + v1.x + v2.x + v3.x;
    ay += v0.y + v1.y + v2.y + v3.y;
  }
  for (; p < pe; p++){
    int s = csr_src[p];
    float2 v = *reinterpret_cast<const float2*>(&Vb[(size_t)s*H]);
    ax += v.x; ay += v.y;
  }
  float2* pp = reinterpret_cast<float2*>(&pre[(size_t)node*H + lane*2]);
  float2 pr = *pp;
  pr.x += ax; pr.y += ay;
  *pp = pr;
}

// ---------- BN stats: per-column sum & sumsq of lrelu(pre) ----------
__global__ __launch_bounds__(256)
void bnstats_kernel(const float* __restrict__ pre, int n, float* __restrict__ bnsum){
  int col  = threadIdx.x & 127;
  int half = threadIdx.x >> 7;
  float s = 0.f, ss = 0.f;
  for (int row = blockIdx.x*2 + half; row < n; row += gridDim.x*2){
    float h = lrelu(pre[(size_t)row*H + col]);
    s += h; ss += h*h;
  }
  __shared__ float sh[2][2][128];
  sh[0][half][col] = s; sh[1][half][col] = ss;
  __syncthreads();
  if (half == 0){
    atomicAdd(&bnsum[col],     sh[0][0][col] + sh[0][1][col]);
    atomicAdd(&bnsum[H + col], sh[1][0][col] + sh[1][1][col]);
  }
}

// ---------- BN finalize -> fused scale/shift: sc = gamma*rsqrt(var+eps), sh = beta - mu*sc ----------
__global__ void bnfin_kernel(const float* __restrict__ bnsum,
                             const float* __restrict__ gamma, const float* __restrict__ beta,
                             float inv_n, float* __restrict__ scsh){
  int c = threadIdx.x;
  float mu  = bnsum[c] * inv_n;
  float var = bnsum[H + c]*inv_n - mu*mu;
  float rs  = rsqrtf(fmaxf(var, 0.f) + EPSBN);
  float sc  = gamma[c] * rs;
  scsh[c]     = sc;
  scsh[H + c] = beta[c] - mu*sc;
}

// ---------- pooled segment-sum of z2 = lrelu(pre2)*sc+sh (8 blocks/graph) ----------
__global__ __launch_bounds__(256)
void pool_kernel(const float* __restrict__ pre, const float* __restrict__ scsh,
                 const int* __restrict__ gofs, float* __restrict__ pooled){
  int g    = blockIdx.x >> 3;
  int part = blockIdx.x & 7;
  int col  = threadIdx.x & 127;
  int half = threadIdx.x >> 7;
  int s = gofs[g], e = gofs[g+1];
  float sc = scsh[col], sh = scsh[H + col];
  float acc = 0.f;
  for (int r = s + part*2 + half; r < e; r += 16)
    acc += lrelu(pre[(size_t)r*H + col])*sc + sh;
  if (acc != 0.f || part == 0)
    atomicAdd(&pooled[(size_t)g*H + col], acc);
}

// ---------- final MLP head: one block per graph ----------
__global__ __launch_bounds__(128)
void head_kernel(const float* __restrict__ pooled, const int* __restrict__ gofs,
                 const float* __restrict__ Wf1, const float* __restrict__ bf1,
                 const float* __restrict__ Wf2, const float* __restrict__ bf2,
                 const float* __restrict__ Wf3, const float* __restrict__ bf3,
                 float* __restrict__ out){
  int g = blockIdx.x;
  int c = threadIdx.x;
  __shared__ float pm[128], h1[128], h2[64];
  float cf = fmaxf((float)(gofs[g+1] - gofs[g]), 1.f);
  pm[c] = pooled[(size_t)g*H + c] / cf;
  __syncthreads();
  float a = bf1[c];
  for (int k=0;k<H;k++) a += pm[k]*Wf1[k*H + c];
  h1[c] = lrelu(a);
  __syncthreads();
  if (c < 64){
    float b = bf2[c];
    for (int k=0;k<H;k++) b += h1[k]*Wf2[k*64 + c];
    h2[c] = lrelu(b);
  }
  __syncthreads();
  if (c < 2){
    float o = bf3[c];
    for (int k=0;k<64;k++) o += h2[k]*Wf3[k*2 + c];
    out[g*2 + c] = o;
  }
}

extern "C" void kernel_launch(void* const* d_in, const int* in_sizes, int n_in,
                              void* d_out, int out_size, void* d_ws, size_t ws_size,
                              hipStream_t stream){
  const float* x     = (const float*)d_in[0];
  const int*   ei    = (const int*)d_in[1];
  const int*   batch = (const int*)d_in[3];
  const float* Wg    = (const float*)d_in[4];
  const float* bg    = (const float*)d_in[5];
  const float* We    = (const float*)d_in[6];
  const float* be    = (const float*)d_in[7];
  const float* Wl    = (const float*)d_in[8];
  const float* bl    = (const float*)d_in[9];
  const float* gamma = (const float*)d_in[10];
  const float* beta  = (const float*)d_in[11];
  const float* Wf1   = (const float*)d_in[12];
  const float* bf1   = (const float*)d_in[13];
  const float* Wf2   = (const float*)d_in[14];
  const float* bf2   = (const float*)d_in[15];
  const float* Wf3   = (const float*)d_in[16];
  const float* bf3   = (const float*)d_in[17];
  float* out = (float*)d_out;

  int n = in_sizes[0] / H;   // 50000
  int E = in_sizes[1] / 2;   // 800000
  int B = out_size / 2;      // 50

  char* ws = (char*)d_ws;
  size_t off = 0;
  auto alloc = [&](size_t bytes)->void*{ void* p = ws + off; off += (bytes + 255) & ~255ULL; return p; };
  float* pre    = (float*)alloc((size_t)n*H*4);
  float* V      = (float*)alloc((size_t)n*H*4);
  float* Mcomb  = (float*)alloc((size_t)3*H*256*4);
  float* Ntmp   = (float*)alloc((size_t)3*H*256*4);
  float* c1c2   = (float*)alloc(3*2*H*4);
  float* scsh   = (float*)alloc(3*2*H*4);
  int*   incl   = (int*)alloc((size_t)n*4);
  int*   bsum   = (int*)alloc(256*4);
  int*   rowptr = (int*)alloc((size_t)(n+1)*4);
  int*   cursor = (int*)alloc((size_t)n*4);
  int*   csr_src= (int*)alloc((size_t)E*4);
  int*   gofs   = (int*)alloc((size_t)(B+1)*4);
  char* zbase = ws + off;                 // ---- zeroed region starts ----
  float* bnsum  = (float*)alloc(3*2*H*4);
  int*   degI   = (int*)alloc((size_t)n*4);
  float* pooled = (float*)alloc((size_t)B*H*4);
  size_t zbytes = (size_t)((ws + off) - zbase);
  hipMemsetAsync(zbase, 0, zbytes, stream);

  prep1_kernel<<<3*H, 256, 0, stream>>>(We, Wl, Ntmp);
  prep2_kernel<<<3*H, 256, 0, stream>>>(Wg, Ntmp, Mcomb);
  prepc_kernel<<<3, 128, 0, stream>>>(be, bg, bl, Wl, c1c2);
  deg_kernel<<<(E+255)/256, 256, 0, stream>>>(ei, E, degI);

  int nb = (n + 255)/256;
  scan1_kernel<<<nb, 256, 0, stream>>>(degI, n, incl, bsum);
  scan2_kernel<<<1, 256, 0, stream>>>(bsum, nb);
  scan3_kernel<<<nb, 256, 0, stream>>>(incl, degI, bsum, n, E, rowptr, cursor);
  fill_kernel<<<(E+255)/256, 256, 0, stream>>>(ei, E, cursor, csr_src);
  gofs_kernel<<<nb, 256, 0, stream>>>(batch, n, B, gofs);

  int gblocks = (n + BM - 1)/BM;
  for (int l=0; l<3; l++){
    if (l == 0)
      gemm_kernel<0><<<gblocks, 256, 0, stream>>>(x, nullptr, Mcomb, c1c2, degI, n, pre, V);
    else
      gemm_kernel<1><<<gblocks, 256, 0, stream>>>(pre, scsh + (l-1)*2*H, Mcomb + (size_t)l*H*256,
                                                  c1c2 + l*2*H, degI, n, pre, V);
    agg_kernel<<<(n+3)/4, 256, 0, stream>>>(rowptr, csr_src, V, pre, n);
    bnstats_kernel<<<512, 256, 0, stream>>>(pre, n, bnsum + l*2*H);
    bnfin_kernel<<<1, 128, 0, stream>>>(bnsum + l*2*H, gamma + l*H, beta + l*H, 1.f/(float)n, scsh + l*2*H);
  }
  pool_kernel<<<B*8, 256, 0, stream>>>(pre, scsh + 2*2*H, gofs, pooled);
  head_kernel<<<B, 128, 0, stream>>>(pooled, gofs, Wf1, bf1, Wf2, bf2, Wf3, bf3, out);
}